// Round 1
// 421.046 us; speedup vs baseline: 1.0347x; 1.0347x over previous
//
#include <hip/hip_runtime.h>

// ---------------------------------------------------------------------------
// TransformerBlock (B=4,S=2048,E=1024,H=16,Dh=64), fp32 (or bf16) in, fp32
// (or bf16) out — dtype auto-detected; all compute in bf16 MFMA w/ fp32 accum.
// Pipeline: cvt-to-bf16 -> fused QKV gemm -> flash attn -> Wo gemm (+x) ->
//           norm1 -> FFN1 (relu) -> FFN2 (+h) -> norm2 -> out
// R7: attn K/V double-buffer with raw s_barrier + s_waitcnt vmcnt(4).
// R8: GEMM rewritten as 256x128-tile, BK=64, 8-wave, 3-buffer deep-prefetch
//     schedule (T3+T4+T5): per K-tile two phases of {ds_read frags ||
//     global_load_lds stage -> s_barrier -> setprio(1) -> 16 MFMA ->
//     setprio(0) -> barrier}; tile-start wait is counted s_waitcnt vmcnt(6)
//     (never 0 in the main loop; prefetch distance = 2 K-tiles).  LDS 144 KB
//     dynamic.  Proven XOR chunk swizzle kept for LDS tiles (T2).
// ---------------------------------------------------------------------------

typedef __attribute__((ext_vector_type(8))) short s16x8;
typedef __attribute__((ext_vector_type(4))) short s16x4;
typedef __attribute__((ext_vector_type(4))) unsigned short u16x4;
typedef __attribute__((ext_vector_type(4))) float f32x4;

__device__ __forceinline__ float bf2f(unsigned short u) {
  unsigned int v = ((unsigned int)u) << 16;
  return __builtin_bit_cast(float, v);
}
__device__ __forceinline__ unsigned short f2bf(float f) {
  unsigned int u = __builtin_bit_cast(unsigned int, f);
  u += 0x7fffu + ((u >> 16) & 1u);   // RNE
  return (unsigned short)(u >> 16);
}
// pack two f32 -> two bf16 (truncate) in one v_perm_b32
__device__ __forceinline__ unsigned int pkbf_trunc(float f0, float f1) {
  return __builtin_amdgcn_perm(__builtin_bit_cast(unsigned int, f1),
                               __builtin_bit_cast(unsigned int, f0), 0x07060302u);
}
__device__ __forceinline__ f32x4 mfma16(s16x8 a, s16x8 b, f32x4 c) {
  return __builtin_amdgcn_mfma_f32_16x16x32_bf16(a, b, c, 0, 0, 0);
}
__device__ __forceinline__ void gl2lds16(const unsigned short* g, unsigned short* l) {
  __builtin_amdgcn_global_load_lds(
      (const __attribute__((address_space(1))) unsigned int*)(g),
      (__attribute__((address_space(3))) unsigned int*)(l), 16, 0, 0);
}

// ---------------------------------------------------------------------------
__global__ void detect_dtype(const unsigned int* __restrict__ x, int* __restrict__ flag) {
  const int tid = threadIdx.x;
  int cnt = 0;
  for (int i = tid; i < 2048; i += 256) {
    const unsigned e = (x[i] >> 7) & 0xFF;
    cnt += (e >= 100 && e <= 150) ? 1 : 0;
  }
#pragma unroll
  for (int off = 32; off >= 1; off >>= 1) cnt += __shfl_xor(cnt, off);
  __shared__ int red[4];
  if ((tid & 63) == 0) red[tid >> 6] = cnt;
  __syncthreads();
  if (tid == 0) *flag = ((red[0] + red[1] + red[2] + red[3]) > 1536) ? 1 : 0;
}

// ---------------------------------------------------------------------------
struct CvtArgs {
  const void* src[17];
  unsigned short* dst[17];
  int cum4[18];
};

__global__ __launch_bounds__(256) void cvt_all(CvtArgs a, const int* __restrict__ flag, int total4) {
  const int i = blockIdx.x * 256 + threadIdx.x;
  if (i >= total4) return;
  int lo = 0, hi = 17;
  while (hi - lo > 1) {
    const int mid = (lo + hi) >> 1;
    if (i >= a.cum4[mid]) lo = mid; else hi = mid;
  }
  const int off4 = i - a.cum4[lo];
  if (*flag) {
    const u16x4* s = (const u16x4*)a.src[lo];
    *(u16x4*)&a.dst[lo][off4 * 4] = s[off4];
  } else {
    const float4* s = (const float4*)a.src[lo];
    const float4 v = s[off4];
    u16x4 o;
    o[0] = f2bf(v.x); o[1] = f2bf(v.y); o[2] = f2bf(v.z); o[3] = f2bf(v.w);
    *(u16x4*)&a.dst[lo][off4 * 4] = o;
  }
}

// ---------------------------------------------------------------------------
// GEMM: C = A(MxK) * W(NxK)^T + bias.   BM=256, BN=128, BK=64, 512 threads.
// 8 waves as 2M x 4N -> per-wave 128x32 output, acc[8][2].
// LDS: 3 K-tile buffers (A 32KB + B 16KB each) = 144KB dynamic.
// Prefetch distance 2 tiles; 6 global_load_lds per tile per thread;
// tile-start wait = vmcnt(6) (counted), vmcnt(0) only on the last tile.
// EPI 2: += resid. EPI 3: relu. EPI 4: fused QKV split (Q scaled, V^T scatter).
// ---------------------------------------------------------------------------
#define QOFF 8388608L
#define SCALE2 0.18033688011f  // (1/8) * log2(e)

template <int EPI>
__global__ __launch_bounds__(512, 1) void gemm8(
    const unsigned short* __restrict__ A, const unsigned short* __restrict__ W,
    const unsigned short* __restrict__ bias, const unsigned short* __restrict__ resid,
    unsigned short* __restrict__ out, int M, int N, int K) {
  extern __shared__ unsigned short sh[];   // 3 * 24576 shorts = 144 KB
  const int tid = threadIdx.x;
  const int lane = tid & 63;
  const int wave = tid >> 6;
  const int qd = lane >> 4;
  const int c = lane & 15;
  const int wr128 = (wave >> 2) * 128;     // 2 M-waves
  const int wc32 = (wave & 3) * 32;        // 4 N-waves
  const long m0 = (long)blockIdx.y * 256;
  const long n0 = (long)blockIdx.x * 128;

  // staging: each thread owns (row = tid>>3, chunk = tid&7); source chunk is
  // XOR-swizzled so LDS dest stays linear (gl2lds constraint), reads unswizzle.
  const int srow = tid >> 3;
  const int scc = ((tid & 7) ^ (srow & 7)) * 8;
  const unsigned short* Asrc = A + (m0 + srow) * (long)K + scc;
  const unsigned short* Wsrc = W + (n0 + srow) * (long)K + scc;
  const int lofs = tid * 8;

  f32x4 acc[8][2] = {};

  // prologue: stage K-tiles 0 and 1 (6 loads each; issue order = age order)
#pragma unroll
  for (int q = 0; q < 4; ++q) gl2lds16(Asrc + (long)q * 64 * K, sh + q * 4096 + lofs);
#pragma unroll
  for (int q = 0; q < 2; ++q) gl2lds16(Wsrc + (long)q * 64 * K, sh + 16384 + q * 4096 + lofs);
#pragma unroll
  for (int q = 0; q < 4; ++q)
    gl2lds16(Asrc + (long)q * 64 * K + 64, sh + 24576 + q * 4096 + lofs);
#pragma unroll
  for (int q = 0; q < 2; ++q)
    gl2lds16(Wsrc + (long)q * 64 * K + 64, sh + 24576 + 16384 + q * 4096 + lofs);

  const int NT = K >> 6;
  int cur = 0;
  for (int t = 0; t < NT; ++t) {
    // tile t landed (all but newest 6 loads = next tile's); then barrier so
    // EVERY wave's staging for tile t is visible before any wave reads it.
    if (t == NT - 1)
      asm volatile("s_waitcnt vmcnt(0)\n\ts_barrier" ::: "memory");
    else
      asm volatile("s_waitcnt vmcnt(6)\n\ts_barrier" ::: "memory");

    const unsigned short* Ac = sh + cur * 24576;
    const unsigned short* Bc = Ac + 16384;
    const int nxt = (cur + 2 >= 3) ? cur - 1 : cur + 2;  // (cur+2)%3
    unsigned short* An = sh + nxt * 24576;
    unsigned short* Bn = An + 16384;
    const bool do_stage = (t + 2 < NT);
    const long kt = (long)(t + 2) * 64;

#pragma unroll
    for (int ph = 0; ph < 2; ++ph) {
      const int ch = ((ph * 4 + qd) ^ (c & 7)) * 8;
      s16x8 af[8], bfr[2];
#pragma unroll
      for (int mt = 0; mt < 8; ++mt)
        af[mt] = *(const s16x8*)&Ac[(wr128 + mt * 16 + c) * 64 + ch];
#pragma unroll
      for (int nt = 0; nt < 2; ++nt)
        bfr[nt] = *(const s16x8*)&Bc[(wc32 + nt * 16 + c) * 64 + ch];
      if (do_stage) {
        if (ph == 0) {  // 3 of tile t+2's 6 load-rounds per phase
          gl2lds16(Asrc + kt, An + lofs);
          gl2lds16(Asrc + (long)64 * K + kt, An + 4096 + lofs);
          gl2lds16(Asrc + (long)128 * K + kt, An + 8192 + lofs);
        } else {
          gl2lds16(Asrc + (long)192 * K + kt, An + 12288 + lofs);
          gl2lds16(Wsrc + kt, Bn + lofs);
          gl2lds16(Wsrc + (long)64 * K + kt, Bn + 4096 + lofs);
        }
      }
      asm volatile("s_barrier" ::: "memory");
      __builtin_amdgcn_s_setprio(1);
#pragma unroll
      for (int mt = 0; mt < 8; ++mt)
#pragma unroll
        for (int nt = 0; nt < 2; ++nt)
          acc[mt][nt] = mfma16(af[mt], bfr[nt], acc[mt][nt]);
      __builtin_amdgcn_s_setprio(0);
      if (ph == 0) asm volatile("s_barrier" ::: "memory");
    }
    cur = (cur + 1 == 3) ? 0 : cur + 1;
  }

#pragma unroll
  for (int nt = 0; nt < 2; ++nt) {
    const int gn = (int)n0 + wc32 + nt * 16 + c;
    const float bv = bf2f(bias[gn]);
#pragma unroll
    for (int mt = 0; mt < 8; ++mt) {
      const long gmb = m0 + wr128 + mt * 16 + qd * 4;
      if constexpr (EPI == 2) {
#pragma unroll
        for (int r = 0; r < 4; ++r) {
          const long gm = gmb + r;
          const float v = acc[mt][nt][r] + bv + bf2f(resid[gm * N + gn]);
          out[gm * N + gn] = f2bf(v);
        }
      } else if constexpr (EPI == 3) {
#pragma unroll
        for (int r = 0; r < 4; ++r) {
          const long gm = gmb + r;
          float v = acc[mt][nt][r] + bv;
          v = fmaxf(v, 0.0f);
          out[gm * N + gn] = f2bf(v);
        }
      } else {  // EPI == 4: fused QKV
        const int seg = gn >> 10;       // 0=Q, 1=K, 2=V  (uniform per block)
        const int nn = gn & 1023;
        if (seg == 0) {                 // Q plain (s,1024), pre-scaled
#pragma unroll
          for (int r = 0; r < 4; ++r)
            out[(gmb + r) * 1024 + nn] = f2bf((acc[mt][nt][r] + bv) * SCALE2);
        } else if (seg == 1) {          // K plain (s,1024)
#pragma unroll
          for (int r = 0; r < 4; ++r)
            (out + QOFF)[(gmb + r) * 1024 + nn] = f2bf(acc[mt][nt][r] + bv);
        } else {                        // V^T (b,h,d,s)
          const int h = nn >> 6, d = nn & 63;
          const long b = gmb >> 11;
          const int s = (int)(gmb & 2047);
          s16x4 pv;
#pragma unroll
          for (int r = 0; r < 4; ++r) pv[r] = (short)f2bf(acc[mt][nt][r] + bv);
          *(s16x4*)&(out + 2 * QOFF)[((b * 16 + h) * 64L + d) * 2048 + s] = pv;
        }
      }
    }
  }
}

// ---------------------------------------------------------------------------
// Flash attention, R7 (unchanged). One workgroup = 256 Q rows of one (b,h).
// KV tile = 64 rows, double-buffered, raw s_barrier + s_waitcnt vmcnt(4).
// ---------------------------------------------------------------------------
#define ATT_S 2048

__global__ __launch_bounds__(256)
__attribute__((amdgpu_waves_per_eu(2, 2))) void attn_fwd(
    const unsigned short* __restrict__ Q, const unsigned short* __restrict__ K,
    const unsigned short* __restrict__ VT, unsigned short* __restrict__ O) {
  __shared__ unsigned short SH[24576];  // 48 KB
  unsigned short* Kb0 = SH;             // [t][d] 64x64 swizzled
  unsigned short* Kb1 = SH + 4096;
  unsigned short* Vb0 = SH + 8192;      // [d][t] 64x64 swizzled
  unsigned short* Vb1 = SH + 12288;
  unsigned short* Pl  = SH + 16384;     // [m][t] 128x64 swizzled

  const int bh = blockIdx.y;
  const int q0 = blockIdx.x * 256;
  const long b = bh >> 4;
  const int h = bh & 15;
  const unsigned short* Qg = Q + (b * 2048) * 1024 + h * 64;
  const unsigned short* Kg = K + (b * 2048) * 1024 + h * 64;
  const unsigned short* Vg = VT + (long)bh * 64 * 2048;

  const int tid = threadIdx.x;
  const int wave = tid >> 6, lane = tid & 63;
  const int qd = lane >> 4, c = lane & 15;
  const int mb = wave * 32;

  const int srow = tid >> 3;
  const int sccs = ((tid & 7) ^ (srow & 7)) * 8;

  s16x8 qf[2][2][2];  // [half][mt][ks]
#pragma unroll
  for (int h2 = 0; h2 < 2; ++h2)
#pragma unroll
    for (int mt = 0; mt < 2; ++mt)
#pragma unroll
      for (int ks = 0; ks < 2; ++ks)
        qf[h2][mt][ks] = *(const s16x8*)&Qg[(long)(q0 + h2 * 128 + mb + mt * 16 + c) * 1024 +
                                            ks * 32 + qd * 8];

  s16x8 ones;
#pragma unroll
  for (int i = 0; i < 8; ++i) ones[i] = (short)0x3F80;

  f32x4 oacc[2][4][2] = {};  // [half][dt][mt]
  f32x4 lacc[2][2] = {};     // [half][mt]

  // preload tile 0
  gl2lds16(Kg + (long)srow * 1024 + sccs, &Kb0[tid * 8]);
  gl2lds16(Kg + (long)(srow + 32) * 1024 + sccs, &Kb0[(256 + tid) * 8]);
  gl2lds16(Vg + (long)srow * 2048 + sccs, &Vb0[tid * 8]);
  gl2lds16(Vg + (long)(srow + 32) * 2048 + sccs, &Vb0[(256 + tid) * 8]);

  for (int it = 0; it < 32; ++it) {
    const int p = it & 1;
    unsigned short* Kc = p ? Kb1 : Kb0;
    unsigned short* Vc = p ? Vb1 : Vb0;
    unsigned short* Kn = p ? Kb0 : Kb1;
    unsigned short* Vn = p ? Vb0 : Vb1;
    const int kvn = (it < 31) ? (it + 1) * 64 : 31 * 64;  // clamp keeps vmcnt math uniform
    gl2lds16(Kg + (long)(kvn + srow) * 1024 + sccs, &Kn[tid * 8]);
    gl2lds16(Kg + (long)(kvn + srow + 32) * 1024 + sccs, &Kn[(256 + tid) * 8]);
    gl2lds16(Vg + (long)srow * 2048 + kvn + sccs, &Vn[tid * 8]);
    gl2lds16(Vg + (long)(srow + 32) * 2048 + kvn + sccs, &Vn[(256 + tid) * 8]);

    // tile `it` fully landed; tile it+1's 4 loads stay in flight
    asm volatile("s_waitcnt vmcnt(4)\n\ts_barrier" ::: "memory");

#pragma unroll
    for (int h2 = 0; h2 < 2; ++h2) {
      f32x4 sacc[4][2] = {};
#pragma unroll
      for (int ks = 0; ks < 2; ++ks) {
        const int ch = ((ks * 4 + qd) ^ (c & 7)) * 8;
        s16x8 kf[4];
#pragma unroll
        for (int tt = 0; tt < 4; ++tt)
          kf[tt] = *(const s16x8*)&Kc[(tt * 16 + c) * 64 + ch];
#pragma unroll
        for (int mt = 0; mt < 2; ++mt)
#pragma unroll
          for (int tt = 0; tt < 4; ++tt)
            sacc[tt][mt] = mfma16(kf[tt], qf[h2][mt][ks], sacc[tt][mt]);
      }

      // exp2 + pack into wave-private P rows (8-chunk XOR swizzle, row len 64)
#pragma unroll
      for (int mt = 0; mt < 2; ++mt) {
        const int ml = mb + mt * 16 + c;
#pragma unroll
        for (int tt = 0; tt < 4; ++tt) {
          unsigned int pk[2];
          pk[0] = pkbf_trunc(__builtin_amdgcn_exp2f(sacc[tt][mt][0]),
                             __builtin_amdgcn_exp2f(sacc[tt][mt][1]));
          pk[1] = pkbf_trunc(__builtin_amdgcn_exp2f(sacc[tt][mt][2]),
                             __builtin_amdgcn_exp2f(sacc[tt][mt][3]));
          const int chw = ((tt * 2 + (qd >> 1)) ^ (ml & 7)) * 8 + (qd & 1) * 4;
          *(uint2*)&Pl[ml * 64 + chw] = *(uint2*)pk;
        }
      }
      asm volatile("s_waitcnt lgkmcnt(0)" ::: "memory");  // own-wave P visible

#pragma unroll
      for (int ks = 0; ks < 2; ++ks) {
        const int vch = ((ks * 4 + qd) ^ (c & 7)) * 8;
        s16x8 vf[4], pf[2];
#pragma unroll
        for (int dt = 0; dt < 4; ++dt)
          vf[dt] = *(const s16x8*)&Vc[(dt * 16 + c) * 64 + vch];
#pragma unroll
        for (int mt = 0; mt < 2; ++mt) {
          const int pr = mb + mt * 16 + c;
          pf[mt] = *(const s16x8*)&Pl[pr * 64 + (((ks * 4 + qd) ^ (pr & 7)) * 8)];
        }
#pragma unroll
        for (int mt = 0; mt < 2; ++mt) {
#pragma unroll
          for (int dt = 0; dt < 4; ++dt)
            oacc[h2][dt][mt] = mfma16(vf[dt], pf[mt], oacc[h2][dt][mt]);
          lacc[h2][mt] = mfma16(ones, pf[mt], lacc[h2][mt]);
        }
      }
    }

    // all waves done reading this buffer before next iter's prefetch hits it
    asm volatile("s_barrier" ::: "memory");
  }

#pragma unroll
  for (int h2 = 0; h2 < 2; ++h2)
#pragma unroll
    for (int mt = 0; mt < 2; ++mt) {
      const float inv = 1.0f / lacc[h2][mt][0];
      const int s = q0 + h2 * 128 + mb + mt * 16 + c;
      const long ob = (b * (long)ATT_S + s) * 1024L + h * 64;
#pragma unroll
      for (int dt = 0; dt < 4; ++dt) {
        s16x4 ov;
#pragma unroll
        for (int r = 0; r < 4; ++r) ov[r] = (short)f2bf(oacc[h2][dt][mt][r] * inv);
        *(s16x4*)&O[ob + dt * 16 + qd * 4] = ov;
      }
    }
}

// ---------------------------------------------------------------------------
template <bool FINAL>
__global__ __launch_bounds__(256) void norm_affine(
    const unsigned short* __restrict__ X, const unsigned short* __restrict__ av,
    const unsigned short* __restrict__ bv, void* __restrict__ outv,
    const int* __restrict__ flag) {
  const int row = blockIdx.x;
  const int s = row & 2047;
  const unsigned short* xr = X + (long)row * 1024;
  const int tid = threadIdx.x;
  const u16x4 u = *(const u16x4*)&xr[tid * 4];
  float v[4];
  float s1 = 0.f, s2 = 0.f;
#pragma unroll
  for (int i = 0; i < 4; ++i) {
    v[i] = bf2f(u[i]);
    s1 += v[i];
    s2 += v[i] * v[i];
  }
#pragma unroll
  for (int off = 32; off >= 1; off >>= 1) {
    s1 += __shfl_xor(s1, off);
    s2 += __shfl_xor(s2, off);
  }
  __shared__ float red[8];
  const int wave = tid >> 6, lane = tid & 63;
  if (lane == 0) {
    red[wave * 2] = s1;
    red[wave * 2 + 1] = s2;
  }
  __syncthreads();
  s1 = red[0] + red[2] + red[4] + red[6];
  s2 = red[1] + red[3] + red[5] + red[7];
  const float mean = s1 * (1.0f / 1024.0f);
  const float var = fmaxf(s2 * (1.0f / 1024.0f) - mean * mean, 0.0f);
  const float rstd = rsqrtf(var + 1e-5f);
  const float aa = bf2f(av[s]), bb = bf2f(bv[s]);
  float o[4];
#pragma unroll
  for (int i = 0; i < 4; ++i) o[i] = aa * (v[i] - mean) * rstd + bb;
  bool as_bf16 = true;
  if constexpr (FINAL) as_bf16 = (*flag != 0);
  if (as_bf16) {
    u16x4 ob;
#pragma unroll
    for (int i = 0; i < 4; ++i) ob[i] = f2bf(o[i]);
    *(u16x4*)&((unsigned short*)outv)[(long)row * 1024 + tid * 4] = ob;
  } else {
    float4 of = {o[0], o[1], o[2], o[3]};
    *(float4*)&((float*)outv)[(long)row * 1024 + tid * 4] = of;
  }
}

// ---------------------------------------------------------------------------
extern "C" void kernel_launch(void* const* d_in, const int* in_sizes, int n_in,
                              void* d_out, int out_size, void* d_ws, size_t ws_size,
                              hipStream_t stream) {
  char* ws = (char*)d_ws;
  const size_t SZ = 8192ull * 1024 * 2;
  const size_t WSZ = 1024ull * 1024 * 2;

  unsigned short* xb   = (unsigned short*)(ws);
  unsigned short* qb   = (unsigned short*)(ws + SZ);   // qb,kb,vtb contiguous
  unsigned short* kb   = (unsigned short*)(ws + 2 * SZ);
  unsigned short* vtb  = (unsigned short*)(ws + 3 * SZ);
  unsigned short* attn = (unsigned short*)(ws + 4 * SZ);
  unsigned short* hb   = (unsigned short*)(ws + 5 * SZ);
  unsigned short* r1   = qb;
  unsigned short* ffb  = kb;
  unsigned short* r2   = attn;

  char* wreg = ws + 6 * SZ;
  unsigned short* wqb = (unsigned short*)(wreg);
  unsigned short* w1b = (unsigned short*)(wreg + 4 * WSZ);
  unsigned short* w2b = (unsigned short*)(wreg + 6 * WSZ);
  unsigned short* wob = (unsigned short*)(wreg + 3 * WSZ);
  unsigned short* smal = (unsigned short*)(wreg + 8 * WSZ);
  unsigned short* bqb = smal;
  unsigned short* bkb = smal + 1024;
  unsigned short* bvb = smal + 2048;
  unsigned short* bob = smal + 3072;
  unsigned short* b1b = smal + 4096;
  unsigned short* b2b = smal + 6144;
  unsigned short* a1b = smal + 7168;
  unsigned short* g1b = smal + 9216;
  unsigned short* a2b = smal + 11264;
  unsigned short* g2b = smal + 13312;
  int* flag = (int*)(wreg + 8 * WSZ + 64 * 1024);

  CvtArgs ca;
  unsigned short* wkb = wqb + 1024 * 1024;
  unsigned short* wvb = wqb + 2 * 1024 * 1024;
  unsigned short* dsts[17] = {xb, wqb, bqb, wkb, bkb, wvb, bvb, wob, bob,
                              a1b, g1b, w1b, b1b, w2b, b2b, a2b, g2b};
  ca.cum4[0] = 0;
  for (int i = 0; i < 17; ++i) {
    ca.src[i] = d_in[i];
    ca.dst[i] = dsts[i];
    ca.cum4[i + 1] = ca.cum4[i] + in_sizes[i] / 4;
  }
  const int total4 = ca.cum4[17];

  // one-time: allow 144 KB dynamic LDS for the gemm8 instantiations
  static bool attr_set = false;
  if (!attr_set) {
    attr_set = true;
    hipFuncSetAttribute(reinterpret_cast<const void*>(gemm8<2>),
                        hipFuncAttributeMaxDynamicSharedMemorySize, 147456);
    hipFuncSetAttribute(reinterpret_cast<const void*>(gemm8<3>),
                        hipFuncAttributeMaxDynamicSharedMemorySize, 147456);
    hipFuncSetAttribute(reinterpret_cast<const void*>(gemm8<4>),
                        hipFuncAttributeMaxDynamicSharedMemorySize, 147456);
  }

  dim3 blk(256);
  dim3 blk512(512);
  const int GLDS = 147456;
  detect_dtype<<<1, blk, 0, stream>>>((const unsigned int*)d_in[0], flag);
  cvt_all<<<(total4 + 255) / 256, blk, 0, stream>>>(ca, flag, total4);

  gemm8<4><<<dim3(24, 32), blk512, GLDS, stream>>>(xb, wqb, bqb, nullptr, qb, 8192, 3072, 1024);
  attn_fwd<<<dim3(8, 64), blk, 0, stream>>>(qb, kb, vtb, attn);
  gemm8<2><<<dim3(8, 32), blk512, GLDS, stream>>>(attn, wob, bob, xb, r1, 8192, 1024, 1024);
  norm_affine<false><<<8192, blk, 0, stream>>>(r1, a1b, g1b, hb, nullptr);
  gemm8<3><<<dim3(16, 32), blk512, GLDS, stream>>>(hb, w1b, b1b, nullptr, ffb, 8192, 2048, 1024);
  gemm8<2><<<dim3(8, 32), blk512, GLDS, stream>>>(ffb, w2b, b2b, hb, r2, 8192, 1024, 2048);
  norm_affine<true><<<8192, blk, 0, stream>>>(r2, a2b, g2b, d_out, flag);
}